// Round 2
// baseline (288.231 us; speedup 1.0000x reference)
//
#include <hip/hip_runtime.h>
#include <stdint.h>

#define OH 250
#define OW 250
#define NPTS (OH*OW)        // 62500
#define SEG 65536           // padded segment length (pow2 >= NPTS)
#define TILE 4096           // LDS bitonic tile
#define NSEG 8              // 4 batches x {x,y}
#define D 147               // 3*7*7
#define CH 3
#define IMH 256
#define IMW 256
#define NITER 17            // ceil(log2(62500)) + 1, per reference

typedef unsigned long long u64;
typedef unsigned int u32;

// workspace layout (bytes)
#define OFF_KEYS  0UL        // u64[8*65536]   = 4,194,304
#define OFF_PAYL  4194304UL  // u32[8*65536]   = 2,097,152
#define OFF_IDX   6291456UL  // int[8*62500]   = 2,000,000
#define OFF_WTS   8291456UL  // double[4*147]  = 4,704
#define OFF_SEGS  8296192UL  // u64[16] per-seg {sum, sumsq}
#define OFF_SUMS  8296320UL  // u64[4] loss accumulators
#define OFF_FLAGS 8296352UL  // u32[1]
#define WS_NEED   8296448UL

__device__ __forceinline__ u64 packd(double f) {
  u64 u = (u64)__double_as_longlong(f);
  return (u & 0x8000000000000000ULL) ? ~u : (u | 0x8000000000000000ULL);
}

__device__ __forceinline__ bool kgt(u64 ka, u32 pa, u64 kb, u32 pb) {
  return (ka > kb) || (ka == kb && pa > pb);
}

// ---- per-batch projection weights: rand / std(rand, ddof=1), f64 ----
__global__ __launch_bounds__(256) void wkern(const float* __restrict__ rnd,
                                             double* __restrict__ wts) {
  __shared__ double red[256];
  int b = blockIdx.x, t = threadIdx.x;
  double val = (t < D) ? (double)rnd[b * D + t] : 0.0;
  red[t] = val;
  __syncthreads();
  for (int s = 128; s > 0; s >>= 1) { if (t < s) red[t] += red[t + s]; __syncthreads(); }
  double mean = red[0] / (double)D;
  __syncthreads();
  double dv = (t < D) ? (val - mean) : 0.0;
  red[t] = dv * dv;
  __syncthreads();
  for (int s = 128; s > 0; s >>= 1) { if (t < s) red[t] += red[t + s]; __syncthreads(); }
  double stdv = sqrt(red[0] / (double)(D - 1));
  if (t < D) wts[b * D + t] = val / stdv;
}

// ---- pad fill + zero accumulators/flags ----
__global__ void init_pad(u64* __restrict__ keys, u32* __restrict__ payl,
                         u64* __restrict__ sums, u64* __restrict__ segs,
                         u32* __restrict__ flags) {
  int t = blockIdx.x * blockDim.x + threadIdx.x;
  if (t < 4) sums[t] = 0ULL;
  if (t < 16) segs[t] = 0ULL;
  if (t == 16) flags[0] = 0u;
  const int pad = SEG - NPTS;                 // 3036
  if (t < NSEG * pad) {
    int s = t / pad, r = t - s * pad;
    keys[(size_t)s * SEG + NPTS + r] = ~0ULL;
    payl[(size_t)s * SEG + NPTS + r] = 0xFFFFFFFFu;
  }
}

// ---- 3x7x7 correlation (f64 accumulate) -> (key, payload) ----
__global__ __launch_bounds__(256) void conv_kern(const float* __restrict__ x,
                                                 const float* __restrict__ y,
                                                 const double* __restrict__ wts,
                                                 u64* __restrict__ keys,
                                                 u32* __restrict__ payl) {
  __shared__ float tile[CH][22][22];
  __shared__ double w[D];
  int s = blockIdx.z;          // 0..3 -> x batches, 4..7 -> y batches
  int b = s & 3;
  const float* in = (s < 4 ? x : y) + (size_t)b * CH * IMH * IMW;
  int bi = blockIdx.y * 16, bj = blockIdx.x * 16;
  int tid = threadIdx.y * 16 + threadIdx.x;
  if (tid < D) w[tid] = wts[b * D + tid];
  for (int c = 0; c < CH; ++c)
    for (int t = tid; t < 22 * 22; t += 256) {
      int rr = t / 22, cc = t - rr * 22;
      int r = bi + rr, col = bj + cc;
      float v = 0.f;
      if (r < IMH && col < IMW) v = in[((size_t)c * IMH + r) * IMW + col];
      tile[c][rr][cc] = v;
    }
  __syncthreads();
  int i = bi + threadIdx.y, j = bj + threadIdx.x;
  if (i < OH && j < OW) {
    double acc = 0.0;
    #pragma unroll
    for (int c = 0; c < CH; ++c)
      #pragma unroll
      for (int ph = 0; ph < 7; ++ph)
        #pragma unroll
        for (int pw = 0; pw < 7; ++pw)
          acc = fma((double)tile[c][threadIdx.y + ph][threadIdx.x + pw],
                    w[c * 49 + ph * 7 + pw], acc);
    int n = i * OW + j;
    keys[(size_t)s * SEG + n] = packd(acc);
    payl[(size_t)s * SEG + n] = (u32)n;
  }
}

// ---- bitonic sort (key+payload): LDS-fused phases k=2..TILE ----
__global__ __launch_bounds__(1024) void bitonic_shared_init(u64* __restrict__ keys,
                                                            u32* __restrict__ payl) {
  __shared__ u64 sk[TILE];
  __shared__ u32 sp[TILE];
  int base = blockIdx.x * TILE;
  for (int t = threadIdx.x; t < TILE; t += 1024) { sk[t] = keys[base + t]; sp[t] = payl[base + t]; }
  for (int k = 2; k <= TILE; k <<= 1)
    for (int j = k >> 1; j > 0; j >>= 1) {
      __syncthreads();
      for (int p = threadIdx.x; p < TILE / 2; p += 1024) {
        int i = ((p & ~(j - 1)) << 1) | (p & (j - 1));
        int l = i | j;
        int gi = (base + i) & (SEG - 1);
        bool asc = ((gi & k) == 0);
        u64 ka = sk[i], kb = sk[l];
        u32 pa = sp[i], pb = sp[l];
        bool sw = asc ? kgt(ka, pa, kb, pb) : kgt(kb, pb, ka, pa);
        if (sw) { sk[i] = kb; sk[l] = ka; sp[i] = pb; sp[l] = pa; }
      }
    }
  __syncthreads();
  for (int t = threadIdx.x; t < TILE; t += 1024) { keys[base + t] = sk[t]; payl[base + t] = sp[t]; }
}

// ---- bitonic sort: one global compare-exchange step ----
__global__ __launch_bounds__(256) void bitonic_global(u64* __restrict__ keys,
                                                      u32* __restrict__ payl, int j, int k) {
  int p = blockIdx.x * 256 + threadIdx.x;
  int i = ((p & ~(j - 1)) << 1) | (p & (j - 1));
  int l = i | j;
  bool asc = (((i & (SEG - 1)) & k) == 0);
  u64 ka = keys[i], kb = keys[l];
  u32 pa = payl[i], pb = payl[l];
  bool sw = asc ? kgt(ka, pa, kb, pb) : kgt(kb, pb, ka, pa);
  if (sw) { keys[i] = kb; keys[l] = ka; payl[i] = pb; payl[l] = pa; }
}

// ---- bitonic sort: LDS-fused tail of phase k ----
__global__ __launch_bounds__(1024) void bitonic_shared_tail(u64* __restrict__ keys,
                                                            u32* __restrict__ payl, int k) {
  __shared__ u64 sk[TILE];
  __shared__ u32 sp[TILE];
  int base = blockIdx.x * TILE;
  for (int t = threadIdx.x; t < TILE; t += 1024) { sk[t] = keys[base + t]; sp[t] = payl[base + t]; }
  for (int j = TILE >> 1; j > 0; j >>= 1) {
    __syncthreads();
    for (int p = threadIdx.x; p < TILE / 2; p += 1024) {
      int i = ((p & ~(j - 1)) << 1) | (p & (j - 1));
      int l = i | j;
      int gi = (base + i) & (SEG - 1);
      bool asc = ((gi & k) == 0);
      u64 ka = sk[i], kb = sk[l];
      u32 pa = sp[i], pb = sp[l];
      bool sw = asc ? kgt(ka, pa, kb, pb) : kgt(kb, pb, ka, pa);
      if (sw) { sk[i] = kb; sk[l] = ka; sp[i] = pb; sp[l] = pa; }
    }
  }
  __syncthreads();
  for (int t = threadIdx.x; t < TILE; t += 1024) { keys[base + t] = sk[t]; payl[base + t] = sp[t]; }
}

// ---- extract argsort + verify sortedness / pad containment ----
__global__ void extract_kern(const u64* __restrict__ keys, const u32* __restrict__ payl,
                             int* __restrict__ idx, u32* __restrict__ flags) {
  int r = blockIdx.x * 256 + threadIdx.x;     // covers SEG
  int s = blockIdx.y;
  size_t base = (size_t)s * SEG;
  if (r < SEG - 1) {
    u64 ka = keys[base + r], kb = keys[base + r + 1];
    u32 pa = payl[base + r], pb = payl[base + r + 1];
    if (kgt(ka, pa, kb, pb)) atomicOr(flags, 1u);                       // order violation
    if (r + 1 < NPTS && ka == kb && pa == pb) atomicOr(flags, 1u);      // dup in live region
  }
  if (r < NPTS) {
    u32 p = payl[base + r];
    if (p >= NPTS) atomicOr(flags, 2u);                                 // pad leaked in
    idx[(size_t)s * NPTS + r] = (int)p;
  }
}

// ---- permutation checksum: per segment sum(n), sum(n^2) ----
__global__ __launch_bounds__(256) void permsum_kern(const int* __restrict__ idx,
                                                    u64* __restrict__ segs) {
  int s = blockIdx.y;
  int r = blockIdx.x * 256 + threadIdx.x;
  u64 v = 0, v2 = 0;
  if (r < NPTS) {
    u64 n = (u64)(u32)idx[(size_t)s * NPTS + r];
    v = n; v2 = n * n;
  }
  for (int off = 32; off > 0; off >>= 1) {
    v  += __shfl_down(v, off, 64);
    v2 += __shfl_down(v2, off, 64);
  }
  __shared__ u64 p1[4], p2[4];
  int lane = threadIdx.x & 63, wid = threadIdx.x >> 6;
  if (lane == 0) { p1[wid] = v; p2[wid] = v2; }
  __syncthreads();
  if (threadIdx.x == 0) {
    atomicAdd(&segs[2 * s],     p1[0] + p1[1] + p1[2] + p1[3]);
    atomicAdd(&segs[2 * s + 1], p2[0] + p2[1] + p2[2] + p2[3]);
  }
}

// ---- exact replica of reference bisect_left-on-unsorted + nearest + sq-diff sum ----
__global__ __launch_bounds__(256) void loss_kern(const int* __restrict__ idx,
                                                 u64* __restrict__ sums) {
  int b = blockIdx.y;
  int i = blockIdx.x * 256 + threadIdx.x;
  const int* ai = idx + (size_t)b * NPTS;        // v values (argsort of proj_x)
  const int* a  = idx + (size_t)(4 + b) * NPTS;  // searched array (argsort of proj_y)
  long long term = 0;
  if (i < NPTS) {
    int v = ai[i];
    int lo = 0, hi = NPTS;
    #pragma unroll
    for (int it = 0; it < NITER; ++it) {
      int mid = (lo + hi) >> 1;
      int cm = mid > NPTS - 1 ? NPTS - 1 : mid;
      int am = a[cm];
      bool go = lo < hi;
      if (go) {
        if (am < v) lo = mid + 1;
        else        hi = mid;
      }
    }
    int pi = lo - 1; if (pi < 0) pi = 0; if (pi > NPTS - 1) pi = NPTS - 1;
    int ci = lo;     if (ci > NPTS - 1) ci = NPTS - 1;
    int ap = a[pi], aa = a[ci];
    int d1 = v - ap; if (d1 < 0) d1 = -d1;
    int d2 = v - aa; if (d2 < 0) d2 = -d2;
    bool take_prev = (lo > 0) && ((lo == NPTS) || (d1 < d2));
    int nearest = take_prev ? ap : aa;
    long long d = (long long)(v - nearest);
    term = d * d;
  }
  for (int off = 32; off > 0; off >>= 1) term += __shfl_down(term, off, 64);
  __shared__ long long part[4];
  int lane = threadIdx.x & 63, wid = threadIdx.x >> 6;
  if (lane == 0) part[wid] = term;
  __syncthreads();
  if (threadIdx.x == 0) {
    long long tot = part[0] + part[1] + part[2] + part[3];
    atomicAdd(&sums[b], (u64)tot);
  }
}

__global__ void final_kern(const u64* __restrict__ sums, const u64* __restrict__ segs,
                           const u32* __restrict__ flags, float* __restrict__ out) {
  if (threadIdx.x == 0 && blockIdx.x == 0) {
    const long long S1 = (long long)NPTS * (NPTS - 1) / 2;
    const long long S2 = ((long long)(NPTS - 1) * NPTS / 2) * (2LL * NPTS - 1) / 3;
    unsigned code = flags[0];                       // bit0: order, bit1: pad leak
    for (int s = 0; s < NSEG; ++s)
      if (segs[2 * s] != (u64)S1 || segs[2 * s + 1] != (u64)S2) code |= 4u;  // not a permutation
    if (code) { out[0] = 1.0e12f * (float)code; return; }
    double l = 0.0;
    for (int b = 0; b < 4; ++b) l += (double)(long long)sums[b] / (double)NPTS;
    out[0] = (float)(l / 4.0);
  }
}

__global__ void guard_kern(float* __restrict__ out) {
  if (threadIdx.x == 0 && blockIdx.x == 0) out[0] = 9.0e12f;  // ws too small sentinel
}

extern "C" void kernel_launch(void* const* d_in, const int* in_sizes, int n_in,
                              void* d_out, int out_size, void* d_ws, size_t ws_size,
                              hipStream_t stream) {
  (void)in_sizes; (void)n_in; (void)out_size;
  if (ws_size < WS_NEED) {
    guard_kern<<<1, 64, 0, stream>>>((float*)d_out);
    return;
  }
  const float* x   = (const float*)d_in[0];
  const float* y   = (const float*)d_in[1];
  const float* rnd = (const float*)d_in[2];

  char* ws = (char*)d_ws;
  u64* keys   = (u64*)(ws + OFF_KEYS);
  u32* payl   = (u32*)(ws + OFF_PAYL);
  int* idx    = (int*)(ws + OFF_IDX);
  double* wts = (double*)(ws + OFF_WTS);
  u64* segs   = (u64*)(ws + OFF_SEGS);
  u64* sums   = (u64*)(ws + OFF_SUMS);
  u32* flags  = (u32*)(ws + OFF_FLAGS);

  wkern<<<4, 256, 0, stream>>>(rnd, wts);
  init_pad<<<(NSEG * (SEG - NPTS) + 255) / 256, 256, 0, stream>>>(keys, payl, sums, segs, flags);
  conv_kern<<<dim3(16, 16, 8), dim3(16, 16), 0, stream>>>(x, y, wts, keys, payl);

  bitonic_shared_init<<<NSEG * SEG / TILE, 1024, 0, stream>>>(keys, payl);
  for (int k = TILE * 2; k <= SEG; k <<= 1) {
    for (int j = k >> 1; j >= TILE; j >>= 1)
      bitonic_global<<<NSEG * SEG / 2 / 256, 256, 0, stream>>>(keys, payl, j, k);
    bitonic_shared_tail<<<NSEG * SEG / TILE, 1024, 0, stream>>>(keys, payl, k);
  }

  extract_kern<<<dim3(SEG / 256, 8), 256, 0, stream>>>(keys, payl, idx, flags);
  permsum_kern<<<dim3((NPTS + 255) / 256, 8), 256, 0, stream>>>(idx, segs);
  loss_kern<<<dim3((NPTS + 255) / 256, 4), 256, 0, stream>>>(idx, sums);
  final_kern<<<1, 64, 0, stream>>>(sums, segs, flags, (float*)d_out);
}